// Round 7
// baseline (344.219 us; speedup 1.0000x reference)
//
#include <hip/hip_runtime.h>
#include <hip/hip_bf16.h>
#include <stdint.h>

// Problem constants (B=4, T=2048, D=256, M=128, L=16, P=2048)
#define TAU 0.35f   // bf16-path score uncertainty window for fp32 refinement

typedef __attribute__((ext_vector_type(8))) short bf16x8;
typedef __attribute__((ext_vector_type(4))) float f32x4;

__device__ __forceinline__ unsigned short f2bf(float f) {
  __bf16 h = (__bf16)f;
  return __builtin_bit_cast(unsigned short, h);
}
__device__ __forceinline__ float bf2f(unsigned short u) {
  unsigned int v = ((unsigned int)u) << 16;
  return __builtin_bit_cast(float, v);
}
__device__ __forceinline__ void async_copy16(const void* g, void* l) {
  __builtin_amdgcn_global_load_lds(
      (const __attribute__((address_space(1))) unsigned int*)g,
      (__attribute__((address_space(3))) unsigned int*)l, 16, 0, 0);
}
__device__ __forceinline__ float rdlane(float v, int l) {
  return __builtin_bit_cast(float,
      __builtin_amdgcn_readlane(__builtin_bit_cast(int, v), l));
}

// ---------------------------------------------------------------------------
// K0: x -> xt2[b][kc][k8][d][8] (bf16, k-slice-major); w1 -> w1t[n][k];
//     logits init; njobs[0..3] zero; featws (16MB) zero for refine atomics.
// ---------------------------------------------------------------------------
__global__ __launch_bounds__(256) void k_prep(
    const float* __restrict__ x, const float* __restrict__ w1,
    const float* __restrict__ b2,
    unsigned short* __restrict__ xt, unsigned short* __restrict__ w1t,
    float* __restrict__ logits, int* __restrict__ njobs,
    float* __restrict__ featws) {
  __shared__ float tileS[64][65];
  __shared__ float tx[64][132];
  int bx = blockIdx.x, tid = threadIdx.x;
  if (bx == 0 && tid < 4) njobs[tid] = 0;
  if (bx < 64) {  // logits init: 16384 floats
    int i = bx * 256 + tid;
    logits[i] = b2[i & 1];
  }
  // zero feat workspace: 2 x 8192 x 256 floats = 1048576 float4
  {
    float4 z = {0.f, 0.f, 0.f, 0.f};
    for (int i = bx * 256 + tid; i < 1048576; i += 304 * 256)
      ((float4*)featws)[i] = z;
  }
  if (bx < 256) {  // x-part: 64 t-rows x 128 d-cols per block
    int b = bx >> 6, kc = (bx >> 1) & 31, dh = bx & 1;
    const float* src = x + ((size_t)b * 2048 + (size_t)kc * 64) * 256 + dh * 128;
#pragma unroll
    for (int p = 0; p < 8; ++p) {
      int idx = p * 256 + tid;
      int row = idx >> 5, f4 = idx & 31;
      *(float4*)&tx[row][f4 * 4] = *(const float4*)&src[(size_t)row * 256 + f4 * 4];
    }
    __syncthreads();
    unsigned short* dst = xt + ((size_t)(b * 32 + kc)) * 16384 + dh * 1024;
#pragma unroll
    for (int p = 0; p < 4; ++p) {
      int idx = p * 256 + tid;
      int d0 = idx & 127, k8 = idx >> 7;
      bf16x8 v;
#pragma unroll
      for (int j = 0; j < 8; ++j) v[j] = (short)f2bf(tx[k8 * 8 + j][d0]);
      *(bf16x8*)&dst[(size_t)k8 * 2048 + d0 * 8] = v;
    }
  } else {  // w1 tiles: k-tiles(12) * n-tiles(4)
    int wt = bx - 256;
    int k6 = wt >> 2, n6 = wt & 3;
    int j = tid & 63, i0 = tid >> 6;
    const float* src = w1 + ((size_t)k6 * 64) * 256 + n6 * 64;
    for (int i = i0; i < 64; i += 4) tileS[i][j] = src[(size_t)i * 256 + j];
    __syncthreads();
    unsigned short* dst = w1t + ((size_t)n6 * 64) * 768 + k6 * 64;
    for (int r = i0; r < 64; r += 4) dst[(size_t)r * 768 + j] = f2bf(tileS[j][r]);
  }
}

// ---------------------------------------------------------------------------
// K1 v5: fetch-once + 4 blocks/CU via BK=32.
//  - block = 32 A-rows x ALL 256 cols (A read exactly once).
//  - LDS 36KB/block: B dbuf 2x16KB ([k8 0..3][col][8], linear DMA),
//    A dbuf 2x2KB ([k8 0..3][row][8], reg-staged fp32->bf16, tid<128).
//  - BK=32 -> 64 iters, 4 MFMA/wave/iter; 4 blocks/CU = 32 waves/CU so a
//    draining block overlaps 3 working ones (the round-6 limiter).
//  - VGPR 52 <= 64 -> launch_bounds(512,8) sustains 4 blocks/CU.
// ---------------------------------------------------------------------------
__global__ __launch_bounds__(512, 8) void k_gemm_rep(
    const float* __restrict__ head, const float* __restrict__ tail,
    const unsigned short* __restrict__ xt,
    float* __restrict__ hrep, float* __restrict__ trep) {
  __shared__ unsigned short As[2][1024];   // [k8 0..3][row 0..31][8]
  __shared__ unsigned short Bs[2][8192];   // [k8 0..3][col 0..255][8]
  int bx = blockIdx.x;
  int b = bx >> 7, mt = bx & 127;   // mt<64: head rowtile, else tail
  const float* Asrc = ((mt < 64) ? head : tail) +
                      ((size_t)(b * 2048 + (mt & 63) * 32)) * 2048;
  float* Crep = (mt < 64) ? hrep : trep;
  const unsigned short* Bsrc = xt + (size_t)b * 524288;

  int tid = threadIdx.x, lane = tid & 63, w = tid >> 6;
  int rg = w & 1, cg = w >> 1;
  int l4 = lane >> 4, l15 = lane & 15;

  // ---- A staging (tid<128): row=tid>>2, k-octet=tid&3 (8 floats) ----
  int arow = tid >> 2, ak8 = tid & 3;
  const float* aptr = Asrc + (size_t)arow * 2048 + ak8 * 8;
  int awi = (ak8 * 32 + arow) * 8;

  // ---- B staging: linear copy, 2 DMA/thread (16KB/iter) ----
  const unsigned short* bg = Bsrc + tid * 8;

  // ---- fragment read offsets (single kh per iter; k8 = l4) ----
  int aoff = (l4 * 32 + rg * 16 + l15) * 8;
  int boff[4];
#pragma unroll
  for (int ct = 0; ct < 4; ++ct)
    boff[ct] = (l4 * 256 + cg * 64 + ct * 16 + l15) * 8;

  f32x4 acc[4];
#pragma unroll
  for (int ct = 0; ct < 4; ++ct) acc[ct] = (f32x4){0.f, 0.f, 0.f, 0.f};

  float4 av0, av1;
  auto STAGEB = [&](int buf) {
#pragma unroll
    for (int a = 0; a < 2; ++a)
      async_copy16(bg + (size_t)a * 4096, &Bs[buf][(tid + a * 512) * 8]);
    bg += 8192;
  };
  auto LOADA = [&]() {
    const float4* ap = (const float4*)aptr;
    av0 = ap[0]; av1 = ap[1];
    aptr += 32;
  };
  auto WRITEA = [&](int buf) {
    bf16x8 p;
    p[0] = (short)f2bf(av0.x); p[1] = (short)f2bf(av0.y);
    p[2] = (short)f2bf(av0.z); p[3] = (short)f2bf(av0.w);
    p[4] = (short)f2bf(av1.x); p[5] = (short)f2bf(av1.y);
    p[6] = (short)f2bf(av1.z); p[7] = (short)f2bf(av1.w);
    *(bf16x8*)&As[buf][awi] = p;
  };
  auto MMA = [&](int buf) {
    const unsigned short* A_ = As[buf];
    const unsigned short* B_ = Bs[buf];
    bf16x8 a0 = *(const bf16x8*)&A_[aoff];
#pragma unroll
    for (int ct = 0; ct < 4; ++ct) {
      bf16x8 bb = *(const bf16x8*)&B_[boff[ct]];
      acc[ct] = __builtin_amdgcn_mfma_f32_16x16x32_bf16(a0, bb, acc[ct], 0, 0, 0);
    }
  };

  STAGEB(0);
  if (tid < 128) { LOADA(); WRITEA(0); }
  __syncthreads();

  for (int it = 0; it < 64; ++it) {
    int cur = it & 1, nxt = cur ^ 1;
    if (it < 63) {
      STAGEB(nxt);
      if (tid < 128) LOADA();
    }
    MMA(cur);
    if (it < 63 && tid < 128) WRITEA(nxt);
    __syncthreads();
  }

  size_t prow = (size_t)b * 2048 + (size_t)(mt & 63) * 32 + rg * 16 + (l4 << 2);
  int cb = cg * 64 + l15;
#pragma unroll
  for (int ct = 0; ct < 4; ++ct)
#pragma unroll
    for (int i = 0; i < 4; ++i)
      Crep[(prow + i) * 256 + cb + ct * 16] = acc[ct][i];
}

// ---------------------------------------------------------------------------
// K2pre: featbf[p][0:256]=h, [256:512]=t, [512:768]=h*t  (bf16)
// ---------------------------------------------------------------------------
__global__ __launch_bounds__(256) void k_feat(
    const float* __restrict__ hrep, const float* __restrict__ trep,
    unsigned short* __restrict__ featbf) {
  int gid = blockIdx.x * 256 + threadIdx.x;
  int p = gid >> 6, d0 = (gid & 63) * 4;
  float4 h4 = *(const float4*)&hrep[(size_t)p * 256 + d0];
  float4 t4 = *(const float4*)&trep[(size_t)p * 256 + d0];
  ushort4 a, bb, c;
  a.x = f2bf(h4.x); a.y = f2bf(h4.y); a.z = f2bf(h4.z); a.w = f2bf(h4.w);
  bb.x = f2bf(t4.x); bb.y = f2bf(t4.y); bb.z = f2bf(t4.z); bb.w = f2bf(t4.w);
  c.x = f2bf(h4.x * t4.x); c.y = f2bf(h4.y * t4.y);
  c.z = f2bf(h4.z * t4.z); c.w = f2bf(h4.w * t4.w);
  *(ushort4*)&featbf[(size_t)p * 768 + d0] = a;
  *(ushort4*)&featbf[(size_t)p * 768 + 256 + d0] = bb;
  *(ushort4*)&featbf[(size_t)p * 768 + 512 + d0] = c;
}

// ---------------------------------------------------------------------------
// K2: relu(feat @ w1 + b1) @ w2 + b2 -> logits (unchanged)
// ---------------------------------------------------------------------------
__global__ __launch_bounds__(256, 4) void k_gemm_mlp(
    const unsigned short* __restrict__ featb, const unsigned short* __restrict__ w1t,
    const float* __restrict__ b1, const float* __restrict__ w2,
    float* __restrict__ logits) {
  __shared__ unsigned short As[2][4096], Bs[2][4096];
  int bx = blockIdx.x;
  int ntile = bx >> 7;
  int mtile = bx & 127;
  int tid = threadIdx.x, lane = tid & 63, w = tid >> 6;

  const unsigned short* ag[2];
  const unsigned short* bgp[2];
  int dofs[2];
#pragma unroll
  for (int a = 0; a < 2; ++a) {
    int rowofs = a * 8 + (lane >> 3);
    int k8 = (lane & 7) ^ (rowofs & 7);
    ag[a] = featb + (size_t)(mtile * 64 + w * 16 + rowofs) * 768 + k8 * 8;
    bgp[a] = w1t + (size_t)(ntile * 64 + w * 16 + rowofs) * 768 + k8 * 8;
    dofs[a] = (w * 128 + a * 64 + lane) * 8;
  }
  int sw0 = (lane >> 4) ^ (lane & 7);
  int sw1 = (4 + (lane >> 4)) ^ (lane & 7);
  int arowc = (w * 16 + (lane & 15)) * 8;
  int colc[4];
#pragma unroll
  for (int ct = 0; ct < 4; ++ct) colc[ct] = (ct * 16 + (lane & 15)) * 8;

  f32x4 acc[4];
#pragma unroll
  for (int ct = 0; ct < 4; ++ct) acc[ct] = (f32x4){0.f, 0.f, 0.f, 0.f};

#pragma unroll
  for (int a = 0; a < 2; ++a) {
    async_copy16(ag[a], &As[0][dofs[a]]); ag[a] += 64;
    async_copy16(bgp[a], &Bs[0][dofs[a]]); bgp[a] += 64;
  }
  __syncthreads();

  for (int it = 0; it < 12; ++it) {
    int cur = it & 1, nxt = cur ^ 1;
    if (it < 11) {
#pragma unroll
      for (int a = 0; a < 2; ++a) {
        async_copy16(ag[a], &As[nxt][dofs[a]]); ag[a] += 64;
        async_copy16(bgp[a], &Bs[nxt][dofs[a]]); bgp[a] += 64;
      }
    }
    const unsigned short* A_ = As[cur];
    const unsigned short* B_ = Bs[cur];
    bf16x8 a0 = *(const bf16x8*)&A_[(arowc + sw0) * 8];
    bf16x8 a1 = *(const bf16x8*)&A_[(arowc + sw1) * 8];
#pragma unroll
    for (int ct = 0; ct < 4; ++ct) {
      bf16x8 b0 = *(const bf16x8*)&B_[(colc[ct] + sw0) * 8];
      acc[ct] = __builtin_amdgcn_mfma_f32_16x16x32_bf16(a0, b0, acc[ct], 0, 0, 0);
    }
#pragma unroll
    for (int ct = 0; ct < 4; ++ct) {
      bf16x8 b1 = *(const bf16x8*)&B_[(colc[ct] + sw1) * 8];
      acc[ct] = __builtin_amdgcn_mfma_f32_16x16x32_bf16(a1, b1, acc[ct], 0, 0, 0);
    }
    __syncthreads();
  }

  float bv[4], w20[4], w21[4];
#pragma unroll
  for (int ct = 0; ct < 4; ++ct) {
    int col = ntile * 64 + ct * 16 + (lane & 15);
    bv[ct] = b1[col]; w20[ct] = w2[col * 2]; w21[ct] = w2[col * 2 + 1];
  }
#pragma unroll
  for (int i = 0; i < 4; ++i) {
    float s0 = 0.f, s1 = 0.f;
#pragma unroll
    for (int ct = 0; ct < 4; ++ct) {
      float r = fmaxf(acc[ct][i] + bv[ct], 0.f);
      s0 += r * w20[ct]; s1 += r * w21[ct];
    }
#pragma unroll
    for (int off = 1; off < 16; off <<= 1) {
      s0 += __shfl_xor(s0, off); s1 += __shfl_xor(s1, off);
    }
    if ((lane & 15) == 0) {
      int row = mtile * 64 + w * 16 + ((lane >> 4) << 2) + i;
      atomicAdd(&logits[row * 2], s0);
      atomicAdd(&logits[row * 2 + 1], s1);
    }
  }
}

// ---------------------------------------------------------------------------
// K3b+K5 fused: per-mention top-1 + uncertainty jobs (bucketed by b) AND
// masked KLDiv mean loss. One block, 512 threads (saves a launch).
// ---------------------------------------------------------------------------
__global__ __launch_bounds__(512) void k_select_loss(
    const float* __restrict__ logits, int* __restrict__ idxv,
    float* __restrict__ mval, int* __restrict__ cmask,
    int* __restrict__ njobs, int* __restrict__ jobs,
    const float* __restrict__ lab, const unsigned char* __restrict__ mask,
    float* __restrict__ out_loss) {
  __shared__ float rs[512], rc[512];
  int tid = threadIdx.x;
  // ---- select phase: q = tid (0..511) ----
  {
    int q = tid;
    int base = q * 16;
    float s[16];
#pragma unroll
    for (int i = 0; i < 16; ++i) s[i] = logits[(size_t)(base + i) * 2 + 1];
    float best = s[0]; int bi = 0;
#pragma unroll
    for (int i = 1; i < 16; ++i) if (s[i] > best) { best = s[i]; bi = i; }
    int msk = 0, cnt = 0;
#pragma unroll
    for (int i = 0; i < 16; ++i) if (s[i] > best - TAU) { msk |= 1 << i; ++cnt; }
    idxv[q] = bi; mval[q] = best;
    if (cnt > 1) {
      cmask[q] = msk;
      int bb = q >> 7;
      for (int i = 0; i < 16; ++i)
        if ((msk >> i) & 1) {
          int j = atomicAdd(&njobs[bb], 1);
          jobs[bb * 2048 + j] = base + i;
        }
    } else cmask[q] = 0;
  }
  // ---- loss phase ----
  float sum = 0.f, cnt = 0.f;
  for (int p = tid; p < 8192; p += 512) {
    float l0 = logits[(size_t)p * 2], l1 = logits[(size_t)p * 2 + 1];
    float a0 = lab[(size_t)p * 2], a1 = lab[(size_t)p * 2 + 1];
    float mx = fmaxf(l0, l1);
    float lse = mx + logf(expf(l0 - mx) + expf(l1 - mx));
    float pw = 0.f;
    if (a0 > 0.f) pw += a0 * logf(fmaxf(a0, 1e-38f));
    if (a1 > 0.f) pw += a1 * logf(fmaxf(a1, 1e-38f));
    pw -= a0 * (l0 - lse) + a1 * (l1 - lse);
    if (mask[p]) { sum += pw; cnt += 1.f; }
  }
  rs[tid] = sum; rc[tid] = cnt;
  __syncthreads();
  for (int s = 256; s > 0; s >>= 1) {
    if (tid < s) { rs[tid] += rs[tid + s]; rc[tid] += rc[tid + s]; }
    __syncthreads();
  }
  if (tid == 0) *out_loss = rs[0] / (rc[0] * 2.0f);
}

// ---------------------------------------------------------------------------
// K3c-A: batched fp32 dot phase (unchanged from round 6).
// ---------------------------------------------------------------------------
__global__ __launch_bounds__(1024) void k_refine_dot(
    const int* __restrict__ njobs, const int* __restrict__ jobs,
    const float* __restrict__ head, const float* __restrict__ tail,
    const float* __restrict__ x,
    float* __restrict__ featH, float* __restrict__ featT) {
  __shared__ float red[4][16][256];   // 64KB
  __shared__ int scode[8];
  int tid = threadIdx.x, lane = tid & 63, w = tid >> 6;
  int tg = w >> 2, dg = w & 3;
  int d = dg * 64 + lane;

  for (int gt = blockIdx.x; ; gt += gridDim.x) {
    int rem = gt, b = 0, nj = 0;
    for (; b < 4; ++b) {
      nj = njobs[b];
      int ntb = ((nj + 7) >> 3) * 8;
      if (rem < ntb) break;
      rem -= ntb;
    }
    if (b == 4) break;
    int grp = rem >> 3, tc = rem & 7;
    __syncthreads();
    if (tid < 8) scode[tid] = jobs[b * 2048 + min(grp * 8 + tid, nj - 1)];
    __syncthreads();

    int t0 = tc * 256 + tg * 64;
    float vh[8], vt[8];
#pragma unroll
    for (int j = 0; j < 8; ++j) {
      int p = scode[j] & 2047;
      size_t ro = ((size_t)(b * 2048 + p)) * 2048 + t0 + lane;
      vh[j] = head[ro]; vt[j] = tail[ro];
    }
    float ah[8] = {0.f, 0.f, 0.f, 0.f, 0.f, 0.f, 0.f, 0.f};
    float at[8] = {0.f, 0.f, 0.f, 0.f, 0.f, 0.f, 0.f, 0.f};
    const float* xp = x + (size_t)b * 524288 + (size_t)t0 * 256 + d;
#pragma unroll 8
    for (int t = 0; t < 64; ++t) {
      float xv = xp[(size_t)t * 256];
#pragma unroll
      for (int j = 0; j < 8; ++j) {
        ah[j] += rdlane(vh[j], t) * xv;
        at[j] += rdlane(vt[j], t) * xv;
      }
    }
#pragma unroll
    for (int j = 0; j < 8; ++j) {
      red[tg][j][d] = ah[j];
      red[tg][8 + j][d] = at[j];
    }
    __syncthreads();
    if (tid < 256) {
#pragma unroll
      for (int j = 0; j < 16; ++j) {
        float s = red[0][j][tid] + red[1][j][tid] + red[2][j][tid] + red[3][j][tid];
        int jj = j & 7;
        if (grp * 8 + jj < nj) {
          float* dst = (j < 8) ? featH : featT;
          atomicAdd(&dst[(size_t)scode[jj] * 256 + tid], s);
        }
      }
    }
  }
}

// ---------------------------------------------------------------------------
// K3c-B: batched MLP phase (unchanged from round 6).
// ---------------------------------------------------------------------------
__global__ __launch_bounds__(1024) void k_refine_mlp(
    const int* __restrict__ njobs, const int* __restrict__ jobs,
    const float* __restrict__ featH, const float* __restrict__ featT,
    const float* __restrict__ w1, const float* __restrict__ b1,
    const float* __restrict__ w2, const float* __restrict__ b2,
    float* __restrict__ refined) {
  __shared__ float feat8[768][8];     // 24KB
  __shared__ float redm[4][8][256];   // 32KB
  __shared__ float part[8][4];
  __shared__ int scode[8];
  int tid = threadIdx.x;
  int hseg = tid >> 8, d = tid & 255;

  for (int gt = blockIdx.x; ; gt += gridDim.x) {
    int rem = gt, b = 0, nj = 0;
    for (; b < 4; ++b) {
      nj = njobs[b];
      int ntb = (nj + 7) >> 3;
      if (rem < ntb) break;
      rem -= ntb;
    }
    if (b == 4) break;
    int grp = rem;
    __syncthreads();
    if (tid < 8) scode[tid] = jobs[b * 2048 + min(grp * 8 + tid, nj - 1)];
    __syncthreads();
#pragma unroll
    for (int r = 0; r < 2; ++r) {
      int j = hseg * 2 + r;
      float h = featH[(size_t)scode[j] * 256 + d];
      float t = featT[(size_t)scode[j] * 256 + d];
      feat8[d][j] = h; feat8[256 + d][j] = t; feat8[512 + d][j] = h * t;
    }
    __syncthreads();
    float hp[8] = {0.f, 0.f, 0.f, 0.f, 0.f, 0.f, 0.f, 0.f};
    const float* w1c = w1 + (size_t)(hseg * 192) * 256 + d;
#pragma unroll 4
    for (int ii = 0; ii < 192; ++ii) {
      float wv = w1c[(size_t)ii * 256];
      float4 f0 = *(const float4*)&feat8[hseg * 192 + ii][0];
      float4 f1 = *(const float4*)&feat8[hseg * 192 + ii][4];
      hp[0] += f0.x * wv; hp[1] += f0.y * wv; hp[2] += f0.z * wv; hp[3] += f0.w * wv;
      hp[4] += f1.x * wv; hp[5] += f1.y * wv; hp[6] += f1.z * wv; hp[7] += f1.w * wv;
    }
#pragma unroll
    for (int j = 0; j < 8; ++j) redm[hseg][j][d] = hp[j];
    __syncthreads();
    if (tid < 256) {
      float w2v = w2[tid * 2 + 1], b1v = b1[tid];
#pragma unroll
      for (int j = 0; j < 8; ++j) {
        float h = b1v + redm[0][j][tid] + redm[1][j][tid] + redm[2][j][tid] + redm[3][j][tid];
        h = fmaxf(h, 0.f) * w2v;
#pragma unroll
        for (int off = 1; off < 64; off <<= 1) h += __shfl_xor(h, off);
        if ((tid & 63) == 0) part[j][tid >> 6] = h;
      }
    }
    __syncthreads();
    if (tid < 8 && grp * 8 + tid < nj)
      refined[scode[tid]] = part[tid][0] + part[tid][1] + part[tid][2] + part[tid][3] + b2[1];
  }
}

// ---------------------------------------------------------------------------
// K4a: rep_m[q][d] = tail_rep[q*16+argmax][d] * max_val
// ---------------------------------------------------------------------------
__global__ __launch_bounds__(256) void k_repm(
    const int* __restrict__ idxv, const float* __restrict__ mval,
    const int* __restrict__ cmask, const float* __restrict__ refined,
    const float* __restrict__ trep, float* __restrict__ repm) {
  int q = blockIdx.x, d = threadIdx.x;
  int mask = cmask[q]; int bi; float v;
  if (mask) {
    bi = -1; v = -1e30f;
    for (int i = 0; i < 16; ++i)
      if ((mask >> i) & 1) { float s = refined[q * 16 + i]; if (s > v) { v = s; bi = i; } }
  } else { bi = idxv[q]; v = mval[q]; }
  repm[(size_t)q * 256 + d] = trep[((size_t)q * 16 + bi) * 256 + d] * v;
}

// ---------------------------------------------------------------------------
// K4b: out[b][t][d] = x + sum_m cmp[b][m][t] * rep_m[b][m][d]  (512 blocks)
// ---------------------------------------------------------------------------
__global__ __launch_bounds__(256) void k_merge(
    const float* __restrict__ cmp, const float* __restrict__ repm,
    const float* __restrict__ x, float* __restrict__ out) {
  __shared__ float cl[128 * 16];
  int bx = blockIdx.x, b = bx >> 7, t0 = (bx & 127) * 16;
  int tid = threadIdx.x;
#pragma unroll
  for (int it = 0; it < 2; ++it) {
    int f = it * 256 + tid;
    int row = f >> 2, c4 = (f & 3) * 4;
    *(float4*)&cl[row * 16 + c4] =
        *(const float4*)&cmp[((size_t)(b * 128 + row)) * 2048 + t0 + c4];
  }
  __syncthreads();
  float acc[16];
#pragma unroll
  for (int i = 0; i < 16; ++i) acc[i] = 0.f;
  int d = tid;
  for (int m = 0; m < 128; ++m) {
    float rv = repm[(size_t)(b * 128 + m) * 256 + d];
    const float4* c4p = (const float4*)&cl[m * 16];
#pragma unroll
    for (int jj = 0; jj < 4; ++jj) {
      float4 c = c4p[jj];
      acc[jj * 4] += c.x * rv; acc[jj * 4 + 1] += c.y * rv;
      acc[jj * 4 + 2] += c.z * rv; acc[jj * 4 + 3] += c.w * rv;
    }
  }
  const float* xb = x + ((size_t)(b * 2048 + t0)) * 256 + d;
  float* ob = out + ((size_t)(b * 2048 + t0)) * 256 + d;
#pragma unroll
  for (int tt = 0; tt < 16; ++tt) ob[(size_t)tt * 256] = xb[(size_t)tt * 256] + acc[tt];
}

// ---------------------------------------------------------------------------
extern "C" void kernel_launch(void* const* d_in, const int* in_sizes, int n_in,
                              void* d_out, int out_size, void* d_ws, size_t ws_size,
                              hipStream_t stream) {
  (void)in_sizes; (void)n_in; (void)out_size; (void)ws_size;
  const float* head = (const float*)d_in[0];
  const float* tail = (const float*)d_in[1];
  // d_in[2] = lens (uniform L=16) -- unused
  const float* x = (const float*)d_in[3];
  const float* cmp = (const float*)d_in[4];
  const float* lab = (const float*)d_in[5];
  const unsigned char* lmask = (const unsigned char*)d_in[6];
  const float* w1 = (const float*)d_in[7];
  const float* b1 = (const float*)d_in[8];
  const float* w2 = (const float*)d_in[9];
  const float* b2 = (const float*)d_in[10];
  float* out = (float*)d_out;

  char* ws = (char*)d_ws;
  size_t off = 0;
  auto alloc = [&](size_t bytes) -> void* {
    void* p = ws + off; off += (bytes + 255) & ~(size_t)255; return p;
  };
  unsigned short* xt = (unsigned short*)alloc(4ull * 256 * 2048 * 2);
  unsigned short* w1t = (unsigned short*)alloc(256ull * 768 * 2);
  float* hrep = (float*)alloc(8192ull * 256 * 4);
  float* trep = (float*)alloc(8192ull * 256 * 4);
  unsigned short* featb = (unsigned short*)alloc(8192ull * 768 * 2);
  float* logits = (float*)alloc(8192ull * 2 * 4);
  float* refined = (float*)alloc(8192ull * 4);
  int* idxv = (int*)alloc(512 * 4);
  float* mvalv = (float*)alloc(512 * 4);
  int* cmaskv = (int*)alloc(512 * 4);
  int* njobs = (int*)alloc(256);
  int* jobs = (int*)alloc(4 * 2048 * 4);
  float* repm = (float*)alloc(512ull * 256 * 4);
  float* featH = (float*)alloc(8192ull * 256 * 4);   // contiguous with featT
  float* featT = (float*)alloc(8192ull * 256 * 4);

  k_prep<<<304, 256, 0, stream>>>(x, w1, b2, xt, w1t, logits, njobs, featH);
  k_gemm_rep<<<512, 512, 0, stream>>>(head, tail, xt, hrep, trep);
  k_feat<<<2048, 256, 0, stream>>>(hrep, trep, featb);
  k_gemm_mlp<<<512, 256, 0, stream>>>(featb, w1t, b1, w2, logits);
  k_select_loss<<<1, 512, 0, stream>>>(logits, idxv, mvalv, cmaskv, njobs, jobs,
                                       lab, lmask, out + 4ull * 2048 * 256);
  k_refine_dot<<<512, 1024, 0, stream>>>(njobs, jobs, head, tail, x, featH, featT);
  k_refine_mlp<<<128, 1024, 0, stream>>>(njobs, jobs, featH, featT, w1, b1, w2, b2, refined);
  k_repm<<<512, 256, 0, stream>>>(idxv, mvalv, cmaskv, refined, trep, repm);
  k_merge<<<512, 256, 0, stream>>>(cmp, repm, x, out);
}

// Round 8
// 344.100 us; speedup vs baseline: 1.0003x; 1.0003x over previous
//
#include <hip/hip_runtime.h>
#include <hip/hip_bf16.h>
#include <stdint.h>

// Problem constants (B=4, T=2048, D=256, M=128, L=16, P=2048)
#define TAU 0.35f   // bf16-path score uncertainty window for fp32 refinement

typedef __attribute__((ext_vector_type(8))) short bf16x8;
typedef __attribute__((ext_vector_type(4))) float f32x4;

__device__ __forceinline__ unsigned short f2bf(float f) {
  __bf16 h = (__bf16)f;
  return __builtin_bit_cast(unsigned short, h);
}
__device__ __forceinline__ float bf2f(unsigned short u) {
  unsigned int v = ((unsigned int)u) << 16;
  return __builtin_bit_cast(float, v);
}
__device__ __forceinline__ void async_copy16(const void* g, void* l) {
  __builtin_amdgcn_global_load_lds(
      (const __attribute__((address_space(1))) unsigned int*)g,
      (__attribute__((address_space(3))) unsigned int*)l, 16, 0, 0);
}
__device__ __forceinline__ float rdlane(float v, int l) {
  return __builtin_bit_cast(float,
      __builtin_amdgcn_readlane(__builtin_bit_cast(int, v), l));
}

// ---------------------------------------------------------------------------
// K0: x -> xt2[b][kc][k8][d][8] (bf16, k-slice-major); w1 -> w1t[n][k];
//     logits init; njobs[0..3] zero; featws (16MB) zero for refine atomics.
// ---------------------------------------------------------------------------
__global__ __launch_bounds__(256) void k_prep(
    const float* __restrict__ x, const float* __restrict__ w1,
    const float* __restrict__ b2,
    unsigned short* __restrict__ xt, unsigned short* __restrict__ w1t,
    float* __restrict__ logits, int* __restrict__ njobs,
    float* __restrict__ featws) {
  __shared__ float tileS[64][65];
  __shared__ float tx[64][132];
  int bx = blockIdx.x, tid = threadIdx.x;
  if (bx == 0 && tid < 4) njobs[tid] = 0;
  if (bx < 64) {  // logits init: 16384 floats
    int i = bx * 256 + tid;
    logits[i] = b2[i & 1];
  }
  // zero feat workspace: 2 x 8192 x 256 floats = 1048576 float4
  {
    float4 z = {0.f, 0.f, 0.f, 0.f};
    for (int i = bx * 256 + tid; i < 1048576; i += 304 * 256)
      ((float4*)featws)[i] = z;
  }
  if (bx < 256) {  // x-part: 64 t-rows x 128 d-cols per block
    int b = bx >> 6, kc = (bx >> 1) & 31, dh = bx & 1;
    const float* src = x + ((size_t)b * 2048 + (size_t)kc * 64) * 256 + dh * 128;
#pragma unroll
    for (int p = 0; p < 8; ++p) {
      int idx = p * 256 + tid;
      int row = idx >> 5, f4 = idx & 31;
      *(float4*)&tx[row][f4 * 4] = *(const float4*)&src[(size_t)row * 256 + f4 * 4];
    }
    __syncthreads();
    unsigned short* dst = xt + ((size_t)(b * 32 + kc)) * 16384 + dh * 1024;
#pragma unroll
    for (int p = 0; p < 4; ++p) {
      int idx = p * 256 + tid;
      int d0 = idx & 127, k8 = idx >> 7;
      bf16x8 v;
#pragma unroll
      for (int j = 0; j < 8; ++j) v[j] = (short)f2bf(tx[k8 * 8 + j][d0]);
      *(bf16x8*)&dst[(size_t)k8 * 2048 + d0 * 8] = v;
    }
  } else {  // w1 tiles: k-tiles(12) * n-tiles(4)
    int wt = bx - 256;
    int k6 = wt >> 2, n6 = wt & 3;
    int j = tid & 63, i0 = tid >> 6;
    const float* src = w1 + ((size_t)k6 * 64) * 256 + n6 * 64;
    for (int i = i0; i < 64; i += 4) tileS[i][j] = src[(size_t)i * 256 + j];
    __syncthreads();
    unsigned short* dst = w1t + ((size_t)n6 * 64) * 768 + k6 * 64;
    for (int r = i0; r < 64; r += 4) dst[(size_t)r * 768 + j] = f2bf(tileS[j][r]);
  }
}

// ---------------------------------------------------------------------------
// K1 v6: BK=64 (32 iters, the round-6 winner) + TRUE 4 blocks/CU via
// column-split:
//  - block = 32 A-rows x 128 cols (col half ch = bx>>9). grid = 1024 =
//    4 blocks/CU, whole grid co-resident.
//  - A read by exactly 2 blocks (bx, bx+512): co-resident AND same XCD
//    (512%8==0) -> 2nd read is an L2 hit; HBM fetch stays ~once.
//  - LDS 40KB/block: B dbuf 2x16KB ([k8][d 0..127][8], linear DMA),
//    A dbuf 2x4KB ([k8][row][8], reg-staged, XOR-swizzled to kill the
//    k8*512B-stride 8-way ds_write bank conflict seen in r6/r7).
//  - r7 lesson: grid must scale with blocks/CU (512 blocks can never
//    exceed 2/CU on 256 CUs).
// ---------------------------------------------------------------------------
__global__ __launch_bounds__(512, 8) void k_gemm_rep(
    const float* __restrict__ head, const float* __restrict__ tail,
    const unsigned short* __restrict__ xt,
    float* __restrict__ hrep, float* __restrict__ trep) {
  __shared__ unsigned short As[2][2048];   // [k8 0..7][row 0..31][8] (swizzled)
  __shared__ unsigned short Bs[2][8192];   // [k8 0..7][d 0..127][8]
  int bx = blockIdx.x;
  int ch = bx >> 9;                 // col half 0/1
  int g = bx & 511;
  int b = g >> 7, mt = g & 127;     // mt<64: head rowtile, else tail
  const float* Asrc = ((mt < 64) ? head : tail) +
                      ((size_t)(b * 2048 + (mt & 63) * 32)) * 2048;
  float* Crep = (mt < 64) ? hrep : trep;
  const unsigned short* Bsrc = xt + (size_t)b * 524288 + ch * 1024;

  int tid = threadIdx.x, lane = tid & 63, w = tid >> 6;
  int rg = w & 1, cg = w >> 1;      // 2 rowgroups x 4 colgroups
  int l4 = lane >> 4, l15 = lane & 15;

  // ---- A staging: thread t: row=t>>4, quad=t&15 (4 floats = 1 float4) ----
  int arow = tid >> 4, aq4 = tid & 15;
  const float* aptr = Asrc + (size_t)arow * 2048 + aq4 * 4;
  int ak8 = aq4 >> 1, ahalf = aq4 & 1;
  int awi = (((ak8 * 32 + arow) * 8 + ahalf * 4)) ^ ((ak8 & 3) << 4);  // swz

  // ---- B staging: 2 DMA/thread; run=k8 (8 runs of 1024 ushorts) ----
  const unsigned short* bg[2];
  int bdst[2];
#pragma unroll
  for (int a = 0; a < 2; ++a) {
    int idx = a * 512 + tid;
    int run = idx >> 7, pos = idx & 127;
    bg[a] = Bsrc + run * 2048 + pos * 8;
    bdst[a] = (run * 128 + pos) * 8;
  }

  // ---- fragment read offsets ----
  int aoff[2];
  int boff[2][2];
#pragma unroll
  for (int kh = 0; kh < 2; ++kh) {
    int k8 = kh * 4 + l4;
    aoff[kh] = (((k8 * 32 + rg * 16 + l15) * 8)) ^ ((k8 & 3) << 4);  // same swz
#pragma unroll
    for (int ct = 0; ct < 2; ++ct)
      boff[kh][ct] = (k8 * 128 + cg * 32 + ct * 16 + l15) * 8;
  }

  f32x4 acc[2];
  acc[0] = (f32x4){0.f, 0.f, 0.f, 0.f};
  acc[1] = (f32x4){0.f, 0.f, 0.f, 0.f};

  float4 av;
  auto STAGEB = [&](int buf) {
#pragma unroll
    for (int a = 0; a < 2; ++a) {
      async_copy16(bg[a], &Bs[buf][bdst[a]]);
      bg[a] += 16384;
    }
  };
  auto LOADA = [&]() {
    av = *(const float4*)aptr;
    aptr += 64;
  };
  auto WRITEA = [&](int buf) {
    ushort4 p;
    p.x = f2bf(av.x); p.y = f2bf(av.y); p.z = f2bf(av.z); p.w = f2bf(av.w);
    *(ushort4*)&As[buf][awi] = p;
  };
  auto MMA = [&](int buf) {
    const unsigned short* A_ = As[buf];
    const unsigned short* B_ = Bs[buf];
#pragma unroll
    for (int kh = 0; kh < 2; ++kh) {
      bf16x8 a0 = *(const bf16x8*)&A_[aoff[kh]];
#pragma unroll
      for (int ct = 0; ct < 2; ++ct) {
        bf16x8 bb = *(const bf16x8*)&B_[boff[kh][ct]];
        acc[ct] = __builtin_amdgcn_mfma_f32_16x16x32_bf16(a0, bb, acc[ct], 0, 0, 0);
      }
    }
  };

  STAGEB(0);
  LOADA();
  WRITEA(0);
  __syncthreads();

  for (int it = 0; it < 32; ++it) {
    int cur = it & 1, nxt = cur ^ 1;
    if (it < 31) {
      STAGEB(nxt);     // B(it+1) DMA: issue early
      LOADA();         // A(it+1) global->reg: issue early
    }
    MMA(cur);          // MFMA covers load latency
    if (it < 31) WRITEA(nxt);   // convert+write late
    __syncthreads();
  }

  // epilogue: C layout col=lane&15, row=(lane>>4)*4+i
  size_t prow = (size_t)b * 2048 + (size_t)(mt & 63) * 32 + rg * 16 + (l4 << 2);
  int cb = ch * 128 + cg * 32 + l15;
#pragma unroll
  for (int ct = 0; ct < 2; ++ct)
#pragma unroll
    for (int i = 0; i < 4; ++i)
      Crep[(prow + i) * 256 + cb + ct * 16] = acc[ct][i];
}

// ---------------------------------------------------------------------------
// K2pre: featbf[p][0:256]=h, [256:512]=t, [512:768]=h*t  (bf16)
// ---------------------------------------------------------------------------
__global__ __launch_bounds__(256) void k_feat(
    const float* __restrict__ hrep, const float* __restrict__ trep,
    unsigned short* __restrict__ featbf) {
  int gid = blockIdx.x * 256 + threadIdx.x;
  int p = gid >> 6, d0 = (gid & 63) * 4;
  float4 h4 = *(const float4*)&hrep[(size_t)p * 256 + d0];
  float4 t4 = *(const float4*)&trep[(size_t)p * 256 + d0];
  ushort4 a, bb, c;
  a.x = f2bf(h4.x); a.y = f2bf(h4.y); a.z = f2bf(h4.z); a.w = f2bf(h4.w);
  bb.x = f2bf(t4.x); bb.y = f2bf(t4.y); bb.z = f2bf(t4.z); bb.w = f2bf(t4.w);
  c.x = f2bf(h4.x * t4.x); c.y = f2bf(h4.y * t4.y);
  c.z = f2bf(h4.z * t4.z); c.w = f2bf(h4.w * t4.w);
  *(ushort4*)&featbf[(size_t)p * 768 + d0] = a;
  *(ushort4*)&featbf[(size_t)p * 768 + 256 + d0] = bb;
  *(ushort4*)&featbf[(size_t)p * 768 + 512 + d0] = c;
}

// ---------------------------------------------------------------------------
// K2: relu(feat @ w1 + b1) @ w2 + b2 -> logits (unchanged)
// ---------------------------------------------------------------------------
__global__ __launch_bounds__(256, 4) void k_gemm_mlp(
    const unsigned short* __restrict__ featb, const unsigned short* __restrict__ w1t,
    const float* __restrict__ b1, const float* __restrict__ w2,
    float* __restrict__ logits) {
  __shared__ unsigned short As[2][4096], Bs[2][4096];
  int bx = blockIdx.x;
  int ntile = bx >> 7;
  int mtile = bx & 127;
  int tid = threadIdx.x, lane = tid & 63, w = tid >> 6;

  const unsigned short* ag[2];
  const unsigned short* bgp[2];
  int dofs[2];
#pragma unroll
  for (int a = 0; a < 2; ++a) {
    int rowofs = a * 8 + (lane >> 3);
    int k8 = (lane & 7) ^ (rowofs & 7);
    ag[a] = featb + (size_t)(mtile * 64 + w * 16 + rowofs) * 768 + k8 * 8;
    bgp[a] = w1t + (size_t)(ntile * 64 + w * 16 + rowofs) * 768 + k8 * 8;
    dofs[a] = (w * 128 + a * 64 + lane) * 8;
  }
  int sw0 = (lane >> 4) ^ (lane & 7);
  int sw1 = (4 + (lane >> 4)) ^ (lane & 7);
  int arowc = (w * 16 + (lane & 15)) * 8;
  int colc[4];
#pragma unroll
  for (int ct = 0; ct < 4; ++ct) colc[ct] = (ct * 16 + (lane & 15)) * 8;

  f32x4 acc[4];
#pragma unroll
  for (int ct = 0; ct < 4; ++ct) acc[ct] = (f32x4){0.f, 0.f, 0.f, 0.f};

#pragma unroll
  for (int a = 0; a < 2; ++a) {
    async_copy16(ag[a], &As[0][dofs[a]]); ag[a] += 64;
    async_copy16(bgp[a], &Bs[0][dofs[a]]); bgp[a] += 64;
  }
  __syncthreads();

  for (int it = 0; it < 12; ++it) {
    int cur = it & 1, nxt = cur ^ 1;
    if (it < 11) {
#pragma unroll
      for (int a = 0; a < 2; ++a) {
        async_copy16(ag[a], &As[nxt][dofs[a]]); ag[a] += 64;
        async_copy16(bgp[a], &Bs[nxt][dofs[a]]); bgp[a] += 64;
      }
    }
    const unsigned short* A_ = As[cur];
    const unsigned short* B_ = Bs[cur];
    bf16x8 a0 = *(const bf16x8*)&A_[(arowc + sw0) * 8];
    bf16x8 a1 = *(const bf16x8*)&A_[(arowc + sw1) * 8];
#pragma unroll
    for (int ct = 0; ct < 4; ++ct) {
      bf16x8 b0 = *(const bf16x8*)&B_[(colc[ct] + sw0) * 8];
      acc[ct] = __builtin_amdgcn_mfma_f32_16x16x32_bf16(a0, b0, acc[ct], 0, 0, 0);
    }
#pragma unroll
    for (int ct = 0; ct < 4; ++ct) {
      bf16x8 b1 = *(const bf16x8*)&B_[(colc[ct] + sw1) * 8];
      acc[ct] = __builtin_amdgcn_mfma_f32_16x16x32_bf16(a1, b1, acc[ct], 0, 0, 0);
    }
    __syncthreads();
  }

  float bv[4], w20[4], w21[4];
#pragma unroll
  for (int ct = 0; ct < 4; ++ct) {
    int col = ntile * 64 + ct * 16 + (lane & 15);
    bv[ct] = b1[col]; w20[ct] = w2[col * 2]; w21[ct] = w2[col * 2 + 1];
  }
#pragma unroll
  for (int i = 0; i < 4; ++i) {
    float s0 = 0.f, s1 = 0.f;
#pragma unroll
    for (int ct = 0; ct < 4; ++ct) {
      float r = fmaxf(acc[ct][i] + bv[ct], 0.f);
      s0 += r * w20[ct]; s1 += r * w21[ct];
    }
#pragma unroll
    for (int off = 1; off < 16; off <<= 1) {
      s0 += __shfl_xor(s0, off); s1 += __shfl_xor(s1, off);
    }
    if ((lane & 15) == 0) {
      int row = mtile * 64 + w * 16 + ((lane >> 4) << 2) + i;
      atomicAdd(&logits[row * 2], s0);
      atomicAdd(&logits[row * 2 + 1], s1);
    }
  }
}

// ---------------------------------------------------------------------------
// K3b+K5 fused: select + masked KLDiv loss (unchanged from round 7)
// ---------------------------------------------------------------------------
__global__ __launch_bounds__(512) void k_select_loss(
    const float* __restrict__ logits, int* __restrict__ idxv,
    float* __restrict__ mval, int* __restrict__ cmask,
    int* __restrict__ njobs, int* __restrict__ jobs,
    const float* __restrict__ lab, const unsigned char* __restrict__ mask,
    float* __restrict__ out_loss) {
  __shared__ float rs[512], rc[512];
  int tid = threadIdx.x;
  {
    int q = tid;
    int base = q * 16;
    float s[16];
#pragma unroll
    for (int i = 0; i < 16; ++i) s[i] = logits[(size_t)(base + i) * 2 + 1];
    float best = s[0]; int bi = 0;
#pragma unroll
    for (int i = 1; i < 16; ++i) if (s[i] > best) { best = s[i]; bi = i; }
    int msk = 0, cnt = 0;
#pragma unroll
    for (int i = 0; i < 16; ++i) if (s[i] > best - TAU) { msk |= 1 << i; ++cnt; }
    idxv[q] = bi; mval[q] = best;
    if (cnt > 1) {
      cmask[q] = msk;
      int bb = q >> 7;
      for (int i = 0; i < 16; ++i)
        if ((msk >> i) & 1) {
          int j = atomicAdd(&njobs[bb], 1);
          jobs[bb * 2048 + j] = base + i;
        }
    } else cmask[q] = 0;
  }
  float sum = 0.f, cnt = 0.f;
  for (int p = tid; p < 8192; p += 512) {
    float l0 = logits[(size_t)p * 2], l1 = logits[(size_t)p * 2 + 1];
    float a0 = lab[(size_t)p * 2], a1 = lab[(size_t)p * 2 + 1];
    float mx = fmaxf(l0, l1);
    float lse = mx + logf(expf(l0 - mx) + expf(l1 - mx));
    float pw = 0.f;
    if (a0 > 0.f) pw += a0 * logf(fmaxf(a0, 1e-38f));
    if (a1 > 0.f) pw += a1 * logf(fmaxf(a1, 1e-38f));
    pw -= a0 * (l0 - lse) + a1 * (l1 - lse);
    if (mask[p]) { sum += pw; cnt += 1.f; }
  }
  rs[tid] = sum; rc[tid] = cnt;
  __syncthreads();
  for (int s = 256; s > 0; s >>= 1) {
    if (tid < s) { rs[tid] += rs[tid + s]; rc[tid] += rc[tid + s]; }
    __syncthreads();
  }
  if (tid == 0) *out_loss = rs[0] / (rc[0] * 2.0f);
}

// ---------------------------------------------------------------------------
// K3c-A: batched fp32 dot phase (unchanged from round 6).
// ---------------------------------------------------------------------------
__global__ __launch_bounds__(1024) void k_refine_dot(
    const int* __restrict__ njobs, const int* __restrict__ jobs,
    const float* __restrict__ head, const float* __restrict__ tail,
    const float* __restrict__ x,
    float* __restrict__ featH, float* __restrict__ featT) {
  __shared__ float red[4][16][256];   // 64KB
  __shared__ int scode[8];
  int tid = threadIdx.x, lane = tid & 63, w = tid >> 6;
  int tg = w >> 2, dg = w & 3;
  int d = dg * 64 + lane;

  for (int gt = blockIdx.x; ; gt += gridDim.x) {
    int rem = gt, b = 0, nj = 0;
    for (; b < 4; ++b) {
      nj = njobs[b];
      int ntb = ((nj + 7) >> 3) * 8;
      if (rem < ntb) break;
      rem -= ntb;
    }
    if (b == 4) break;
    int grp = rem >> 3, tc = rem & 7;
    __syncthreads();
    if (tid < 8) scode[tid] = jobs[b * 2048 + min(grp * 8 + tid, nj - 1)];
    __syncthreads();

    int t0 = tc * 256 + tg * 64;
    float vh[8], vt[8];
#pragma unroll
    for (int j = 0; j < 8; ++j) {
      int p = scode[j] & 2047;
      size_t ro = ((size_t)(b * 2048 + p)) * 2048 + t0 + lane;
      vh[j] = head[ro]; vt[j] = tail[ro];
    }
    float ah[8] = {0.f, 0.f, 0.f, 0.f, 0.f, 0.f, 0.f, 0.f};
    float at[8] = {0.f, 0.f, 0.f, 0.f, 0.f, 0.f, 0.f, 0.f};
    const float* xp = x + (size_t)b * 524288 + (size_t)t0 * 256 + d;
#pragma unroll 8
    for (int t = 0; t < 64; ++t) {
      float xv = xp[(size_t)t * 256];
#pragma unroll
      for (int j = 0; j < 8; ++j) {
        ah[j] += rdlane(vh[j], t) * xv;
        at[j] += rdlane(vt[j], t) * xv;
      }
    }
#pragma unroll
    for (int j = 0; j < 8; ++j) {
      red[tg][j][d] = ah[j];
      red[tg][8 + j][d] = at[j];
    }
    __syncthreads();
    if (tid < 256) {
#pragma unroll
      for (int j = 0; j < 16; ++j) {
        float s = red[0][j][tid] + red[1][j][tid] + red[2][j][tid] + red[3][j][tid];
        int jj = j & 7;
        if (grp * 8 + jj < nj) {
          float* dst = (j < 8) ? featH : featT;
          atomicAdd(&dst[(size_t)scode[jj] * 256 + tid], s);
        }
      }
    }
  }
}

// ---------------------------------------------------------------------------
// K3c-B: batched MLP phase (unchanged from round 6).
// ---------------------------------------------------------------------------
__global__ __launch_bounds__(1024) void k_refine_mlp(
    const int* __restrict__ njobs, const int* __restrict__ jobs,
    const float* __restrict__ featH, const float* __restrict__ featT,
    const float* __restrict__ w1, const float* __restrict__ b1,
    const float* __restrict__ w2, const float* __restrict__ b2,
    float* __restrict__ refined) {
  __shared__ float feat8[768][8];     // 24KB
  __shared__ float redm[4][8][256];   // 32KB
  __shared__ float part[8][4];
  __shared__ int scode[8];
  int tid = threadIdx.x;
  int hseg = tid >> 8, d = tid & 255;

  for (int gt = blockIdx.x; ; gt += gridDim.x) {
    int rem = gt, b = 0, nj = 0;
    for (; b < 4; ++b) {
      nj = njobs[b];
      int ntb = (nj + 7) >> 3;
      if (rem < ntb) break;
      rem -= ntb;
    }
    if (b == 4) break;
    int grp = rem;
    __syncthreads();
    if (tid < 8) scode[tid] = jobs[b * 2048 + min(grp * 8 + tid, nj - 1)];
    __syncthreads();
#pragma unroll
    for (int r = 0; r < 2; ++r) {
      int j = hseg * 2 + r;
      float h = featH[(size_t)scode[j] * 256 + d];
      float t = featT[(size_t)scode[j] * 256 + d];
      feat8[d][j] = h; feat8[256 + d][j] = t; feat8[512 + d][j] = h * t;
    }
    __syncthreads();
    float hp[8] = {0.f, 0.f, 0.f, 0.f, 0.f, 0.f, 0.f, 0.f};
    const float* w1c = w1 + (size_t)(hseg * 192) * 256 + d;
#pragma unroll 4
    for (int ii = 0; ii < 192; ++ii) {
      float wv = w1c[(size_t)ii * 256];
      float4 f0 = *(const float4*)&feat8[hseg * 192 + ii][0];
      float4 f1 = *(const float4*)&feat8[hseg * 192 + ii][4];
      hp[0] += f0.x * wv; hp[1] += f0.y * wv; hp[2] += f0.z * wv; hp[3] += f0.w * wv;
      hp[4] += f1.x * wv; hp[5] += f1.y * wv; hp[6] += f1.z * wv; hp[7] += f1.w * wv;
    }
#pragma unroll
    for (int j = 0; j < 8; ++j) redm[hseg][j][d] = hp[j];
    __syncthreads();
    if (tid < 256) {
      float w2v = w2[tid * 2 + 1], b1v = b1[tid];
#pragma unroll
      for (int j = 0; j < 8; ++j) {
        float h = b1v + redm[0][j][tid] + redm[1][j][tid] + redm[2][j][tid] + redm[3][j][tid];
        h = fmaxf(h, 0.f) * w2v;
#pragma unroll
        for (int off = 1; off < 64; off <<= 1) h += __shfl_xor(h, off);
        if ((tid & 63) == 0) part[j][tid >> 6] = h;
      }
    }
    __syncthreads();
    if (tid < 8 && grp * 8 + tid < nj)
      refined[scode[tid]] = part[tid][0] + part[tid][1] + part[tid][2] + part[tid][3] + b2[1];
  }
}

// ---------------------------------------------------------------------------
// K4a: rep_m[q][d] = tail_rep[q*16+argmax][d] * max_val
// ---------------------------------------------------------------------------
__global__ __launch_bounds__(256) void k_repm(
    const int* __restrict__ idxv, const float* __restrict__ mval,
    const int* __restrict__ cmask, const float* __restrict__ refined,
    const float* __restrict__ trep, float* __restrict__ repm) {
  int q = blockIdx.x, d = threadIdx.x;
  int mask = cmask[q]; int bi; float v;
  if (mask) {
    bi = -1; v = -1e30f;
    for (int i = 0; i < 16; ++i)
      if ((mask >> i) & 1) { float s = refined[q * 16 + i]; if (s > v) { v = s; bi = i; } }
  } else { bi = idxv[q]; v = mval[q]; }
  repm[(size_t)q * 256 + d] = trep[((size_t)q * 16 + bi) * 256 + d] * v;
}

// ---------------------------------------------------------------------------
// K4b: out[b][t][d] = x + sum_m cmp[b][m][t] * rep_m[b][m][d]  (512 blocks)
// ---------------------------------------------------------------------------
__global__ __launch_bounds__(256) void k_merge(
    const float* __restrict__ cmp, const float* __restrict__ repm,
    const float* __restrict__ x, float* __restrict__ out) {
  __shared__ float cl[128 * 16];
  int bx = blockIdx.x, b = bx >> 7, t0 = (bx & 127) * 16;
  int tid = threadIdx.x;
#pragma unroll
  for (int it = 0; it < 2; ++it) {
    int f = it * 256 + tid;
    int row = f >> 2, c4 = (f & 3) * 4;
    *(float4*)&cl[row * 16 + c4] =
        *(const float4*)&cmp[((size_t)(b * 128 + row)) * 2048 + t0 + c4];
  }
  __syncthreads();
  float acc[16];
#pragma unroll
  for (int i = 0; i < 16; ++i) acc[i] = 0.f;
  int d = tid;
  for (int m = 0; m < 128; ++m) {
    float rv = repm[(size_t)(b * 128 + m) * 256 + d];
    const float4* c4p = (const float4*)&cl[m * 16];
#pragma unroll
    for (int jj = 0; jj < 4; ++jj) {
      float4 c = c4p[jj];
      acc[jj * 4] += c.x * rv; acc[jj * 4 + 1] += c.y * rv;
      acc[jj * 4 + 2] += c.z * rv; acc[jj * 4 + 3] += c.w * rv;
    }
  }
  const float* xb = x + ((size_t)(b * 2048 + t0)) * 256 + d;
  float* ob = out + ((size_t)(b * 2048 + t0)) * 256 + d;
#pragma unroll
  for (int tt = 0; tt < 16; ++tt) ob[(size_t)tt * 256] = xb[(size_t)tt * 256] + acc[tt];
}

// ---------------------------------------------------------------------------
extern "C" void kernel_launch(void* const* d_in, const int* in_sizes, int n_in,
                              void* d_out, int out_size, void* d_ws, size_t ws_size,
                              hipStream_t stream) {
  (void)in_sizes; (void)n_in; (void)out_size; (void)ws_size;
  const float* head = (const float*)d_in[0];
  const float* tail = (const float*)d_in[1];
  // d_in[2] = lens (uniform L=16) -- unused
  const float* x = (const float*)d_in[3];
  const float* cmp = (const float*)d_in[4];
  const float* lab = (const float*)d_in[5];
  const unsigned char* lmask = (const unsigned char*)d_in[6];
  const float* w1 = (const float*)d_in[7];
  const float* b1 = (const float*)d_in[8];
  const float* w2 = (const float*)d_in[9];
  const float* b2 = (const float*)d_in[10];
  float* out = (float*)d_out;

  char* ws = (char*)d_ws;
  size_t off = 0;
  auto alloc = [&](size_t bytes) -> void* {
    void* p = ws + off; off += (bytes + 255) & ~(size_t)255; return p;
  };
  unsigned short* xt = (unsigned short*)alloc(4ull * 256 * 2048 * 2);
  unsigned short* w1t = (unsigned short*)alloc(256ull * 768 * 2);
  float* hrep = (float*)alloc(8192ull * 256 * 4);
  float* trep = (float*)alloc(8192ull * 256 * 4);
  unsigned short* featb = (unsigned short*)alloc(8192ull * 768 * 2);
  float* logits = (float*)alloc(8192ull * 2 * 4);
  float* refined = (float*)alloc(8192ull * 4);
  int* idxv = (int*)alloc(512 * 4);
  float* mvalv = (float*)alloc(512 * 4);
  int* cmaskv = (int*)alloc(512 * 4);
  int* njobs = (int*)alloc(256);
  int* jobs = (int*)alloc(4 * 2048 * 4);
  float* repm = (float*)alloc(512ull * 256 * 4);
  float* featH = (float*)alloc(8192ull * 256 * 4);   // contiguous with featT
  float* featT = (float*)alloc(8192ull * 256 * 4);

  k_prep<<<304, 256, 0, stream>>>(x, w1, b2, xt, w1t, logits, njobs, featH);
  k_gemm_rep<<<1024, 512, 0, stream>>>(head, tail, xt, hrep, trep);
  k_feat<<<2048, 256, 0, stream>>>(hrep, trep, featb);
  k_gemm_mlp<<<512, 256, 0, stream>>>(featb, w1t, b1, w2, logits);
  k_select_loss<<<1, 512, 0, stream>>>(logits, idxv, mvalv, cmaskv, njobs, jobs,
                                       lab, lmask, out + 4ull * 2048 * 256);
  k_refine_dot<<<512, 1024, 0, stream>>>(njobs, jobs, head, tail, x, featH, featT);
  k_refine_mlp<<<128, 1024, 0, stream>>>(njobs, jobs, featH, featT, w1, b1, w2, b2, refined);
  k_repm<<<512, 256, 0, stream>>>(idxv, mvalv, cmaskv, refined, trep, repm);
  k_merge<<<512, 256, 0, stream>>>(cmp, repm, x, out);
}

// Round 9
// 328.302 us; speedup vs baseline: 1.0485x; 1.0481x over previous
//
#include <hip/hip_runtime.h>
#include <hip/hip_bf16.h>
#include <stdint.h>

// Problem constants (B=4, T=2048, D=256, M=128, L=16, P=2048)
#define TAU 0.35f   // bf16-path score uncertainty window for fp32 refinement

typedef __attribute__((ext_vector_type(8))) short bf16x8;
typedef __attribute__((ext_vector_type(4))) float f32x4;

__device__ __forceinline__ unsigned short f2bf(float f) {
  __bf16 h = (__bf16)f;
  return __builtin_bit_cast(unsigned short, h);
}
__device__ __forceinline__ float bf2f(unsigned short u) {
  unsigned int v = ((unsigned int)u) << 16;
  return __builtin_bit_cast(float, v);
}
__device__ __forceinline__ void async_copy16(const void* g, void* l) {
  __builtin_amdgcn_global_load_lds(
      (const __attribute__((address_space(1))) unsigned int*)g,
      (__attribute__((address_space(3))) unsigned int*)l, 16, 0, 0);
}
__device__ __forceinline__ float rdlane(float v, int l) {
  return __builtin_bit_cast(float,
      __builtin_amdgcn_readlane(__builtin_bit_cast(int, v), l));
}

// ---------------------------------------------------------------------------
// K0: x -> xt2[b][kc][k8][d][8] (bf16, k-slice-major); w1 -> w1t[n][k];
//     logits init; njobs[0..3] zero; featws (16MB) zero for refine atomics.
// ---------------------------------------------------------------------------
__global__ __launch_bounds__(256) void k_prep(
    const float* __restrict__ x, const float* __restrict__ w1,
    const float* __restrict__ b2,
    unsigned short* __restrict__ xt, unsigned short* __restrict__ w1t,
    float* __restrict__ logits, int* __restrict__ njobs,
    float* __restrict__ featws) {
  __shared__ float tileS[64][65];
  __shared__ float tx[64][132];
  int bx = blockIdx.x, tid = threadIdx.x;
  if (bx == 0 && tid < 4) njobs[tid] = 0;
  if (bx < 64) {  // logits init: 16384 floats
    int i = bx * 256 + tid;
    logits[i] = b2[i & 1];
  }
  // zero feat workspace: 2 x 8192 x 256 floats = 1048576 float4
  {
    float4 z = {0.f, 0.f, 0.f, 0.f};
    for (int i = bx * 256 + tid; i < 1048576; i += 304 * 256)
      ((float4*)featws)[i] = z;
  }
  if (bx < 256) {  // x-part: 64 t-rows x 128 d-cols per block
    int b = bx >> 6, kc = (bx >> 1) & 31, dh = bx & 1;
    const float* src = x + ((size_t)b * 2048 + (size_t)kc * 64) * 256 + dh * 128;
#pragma unroll
    for (int p = 0; p < 8; ++p) {
      int idx = p * 256 + tid;
      int row = idx >> 5, f4 = idx & 31;
      *(float4*)&tx[row][f4 * 4] = *(const float4*)&src[(size_t)row * 256 + f4 * 4];
    }
    __syncthreads();
    unsigned short* dst = xt + ((size_t)(b * 32 + kc)) * 16384 + dh * 1024;
#pragma unroll
    for (int p = 0; p < 4; ++p) {
      int idx = p * 256 + tid;
      int d0 = idx & 127, k8 = idx >> 7;
      bf16x8 v;
#pragma unroll
      for (int j = 0; j < 8; ++j) v[j] = (short)f2bf(tx[k8 * 8 + j][d0]);
      *(bf16x8*)&dst[(size_t)k8 * 2048 + d0 * 8] = v;
    }
  } else {  // w1 tiles: k-tiles(12) * n-tiles(4)
    int wt = bx - 256;
    int k6 = wt >> 2, n6 = wt & 3;
    int j = tid & 63, i0 = tid >> 6;
    const float* src = w1 + ((size_t)k6 * 64) * 256 + n6 * 64;
    for (int i = i0; i < 64; i += 4) tileS[i][j] = src[(size_t)i * 256 + j];
    __syncthreads();
    unsigned short* dst = w1t + ((size_t)n6 * 64) * 768 + k6 * 64;
    for (int r = i0; r < 64; r += 4) dst[(size_t)r * 768 + j] = f2bf(tileS[j][r]);
  }
}

// ---------------------------------------------------------------------------
// K1 v7: the round-6 winner (fetch-once, BK=64, 32r x 256c, 2 blocks/CU,
// grid 512, measured 63us) with two cheap fixes:
//  - A-LDS XOR swizzle: awi ^= (ak8&3)<<4 (ushorts) kills the k8*512B-stride
//    8-way ds_write/read bank conflict (3.67M cycles in r6; r8 validated
//    the swizzle form).
//  - XCD-aware remap wgid=(bx&7)*64+(bx>>3) (bijective, 512%8==0): under
//    round-robin dispatch each XCD then works ONE batch's 1MB B-panel in
//    its 4MB L2 instead of juggling all 4 panels.
// r8 lesson kept: no decomposition that re-reads A (dur == FETCH/achieved-BW;
// col-split's +53MB beat its +0.4TB/s).
// ---------------------------------------------------------------------------
__global__ __launch_bounds__(512, 4) void k_gemm_rep(
    const float* __restrict__ head, const float* __restrict__ tail,
    const unsigned short* __restrict__ xt,
    float* __restrict__ hrep, float* __restrict__ trep) {
  __shared__ unsigned short As[2][2048];   // [k8][row][8], XOR-swizzled
  __shared__ unsigned short Bs[2][16384];  // [k8][col][8]
  int bx0 = blockIdx.x;
  int bx = ((bx0 & 7) << 6) | (bx0 >> 3);  // XCD remap (grid 512)
  int b = bx >> 7, mt = bx & 127;   // mt<64: head rowtile, else tail
  const float* Asrc = ((mt < 64) ? head : tail) +
                      ((size_t)(b * 2048 + (mt & 63) * 32)) * 2048;
  float* Crep = (mt < 64) ? hrep : trep;
  const unsigned short* Bsrc = xt + (size_t)b * 524288;

  int tid = threadIdx.x, lane = tid & 63, w = tid >> 6;
  int rg = w & 1, cg = w >> 1;
  int l4 = lane >> 4, l15 = lane & 15;

  // ---- A staging (tid<256): row=tid>>3, k-octet=tid&7 ----
  int arow = tid >> 3, ak8 = tid & 7;
  const float* aptr = Asrc + (size_t)arow * 2048 + ak8 * 8;
  int awi = ((ak8 * 32 + arow) * 8) ^ ((ak8 & 3) << 4);   // swizzled

  // ---- B staging: linear copy, 4 DMA/thread ----
  const unsigned short* bg = Bsrc + tid * 8;

  // ---- fragment read offsets (swizzle matches A write) ----
  int aoff[2];
  int boff[2][4];
#pragma unroll
  for (int kh = 0; kh < 2; ++kh) {
    int k8 = kh * 4 + l4;
    aoff[kh] = (((k8 * 32 + rg * 16 + l15) * 8)) ^ ((l4 & 3) << 4);
#pragma unroll
    for (int ct = 0; ct < 4; ++ct)
      boff[kh][ct] = (k8 * 256 + cg * 64 + ct * 16 + l15) * 8;
  }

  f32x4 acc[4];
#pragma unroll
  for (int ct = 0; ct < 4; ++ct) acc[ct] = (f32x4){0.f, 0.f, 0.f, 0.f};

  float4 av0, av1;
  auto STAGEB = [&](int buf) {
#pragma unroll
    for (int a = 0; a < 4; ++a)
      async_copy16(bg + (size_t)a * 4096, &Bs[buf][(tid + a * 512) * 8]);
    bg += 16384;
  };
  auto LOADA = [&]() {
    const float4* ap = (const float4*)aptr;
    av0 = ap[0]; av1 = ap[1];
    aptr += 64;
  };
  auto WRITEA = [&](int buf) {
    bf16x8 p;
    p[0] = (short)f2bf(av0.x); p[1] = (short)f2bf(av0.y);
    p[2] = (short)f2bf(av0.z); p[3] = (short)f2bf(av0.w);
    p[4] = (short)f2bf(av1.x); p[5] = (short)f2bf(av1.y);
    p[6] = (short)f2bf(av1.z); p[7] = (short)f2bf(av1.w);
    *(bf16x8*)&As[buf][awi] = p;
  };
  auto MMA = [&](int buf) {
    const unsigned short* A_ = As[buf];
    const unsigned short* B_ = Bs[buf];
#pragma unroll
    for (int kh = 0; kh < 2; ++kh) {
      bf16x8 a0 = *(const bf16x8*)&A_[aoff[kh]];
#pragma unroll
      for (int ct = 0; ct < 4; ++ct) {
        bf16x8 bb = *(const bf16x8*)&B_[boff[kh][ct]];
        acc[ct] = __builtin_amdgcn_mfma_f32_16x16x32_bf16(a0, bb, acc[ct], 0, 0, 0);
      }
    }
  };

  STAGEB(0);
  if (tid < 256) { LOADA(); WRITEA(0); }
  __syncthreads();

  for (int it = 0; it < 32; ++it) {
    int cur = it & 1, nxt = cur ^ 1;
    if (it < 31) {
      STAGEB(nxt);                 // B(it+1) DMA: issue early
      if (tid < 256) LOADA();      // A(it+1) global->reg: issue early
    }
    MMA(cur);                      // MFMA covers A-load latency
    if (it < 31 && tid < 256) WRITEA(nxt);  // convert+write late
    __syncthreads();
  }

  size_t prow = (size_t)b * 2048 + (size_t)(mt & 63) * 32 + rg * 16 + (l4 << 2);
  int cb = cg * 64 + l15;
#pragma unroll
  for (int ct = 0; ct < 4; ++ct)
#pragma unroll
    for (int i = 0; i < 4; ++i)
      Crep[(prow + i) * 256 + cb + ct * 16] = acc[ct][i];
}

// ---------------------------------------------------------------------------
// K2pre: featbf[p][0:256]=h, [256:512]=t, [512:768]=h*t  (bf16)
// ---------------------------------------------------------------------------
__global__ __launch_bounds__(256) void k_feat(
    const float* __restrict__ hrep, const float* __restrict__ trep,
    unsigned short* __restrict__ featbf) {
  int gid = blockIdx.x * 256 + threadIdx.x;
  int p = gid >> 6, d0 = (gid & 63) * 4;
  float4 h4 = *(const float4*)&hrep[(size_t)p * 256 + d0];
  float4 t4 = *(const float4*)&trep[(size_t)p * 256 + d0];
  ushort4 a, bb, c;
  a.x = f2bf(h4.x); a.y = f2bf(h4.y); a.z = f2bf(h4.z); a.w = f2bf(h4.w);
  bb.x = f2bf(t4.x); bb.y = f2bf(t4.y); bb.z = f2bf(t4.z); bb.w = f2bf(t4.w);
  c.x = f2bf(h4.x * t4.x); c.y = f2bf(h4.y * t4.y);
  c.z = f2bf(h4.z * t4.z); c.w = f2bf(h4.w * t4.w);
  *(ushort4*)&featbf[(size_t)p * 768 + d0] = a;
  *(ushort4*)&featbf[(size_t)p * 768 + 256 + d0] = bb;
  *(ushort4*)&featbf[(size_t)p * 768 + 512 + d0] = c;
}

// ---------------------------------------------------------------------------
// K2: relu(feat @ w1 + b1) @ w2 + b2 -> logits (unchanged)
// ---------------------------------------------------------------------------
__global__ __launch_bounds__(256, 4) void k_gemm_mlp(
    const unsigned short* __restrict__ featb, const unsigned short* __restrict__ w1t,
    const float* __restrict__ b1, const float* __restrict__ w2,
    float* __restrict__ logits) {
  __shared__ unsigned short As[2][4096], Bs[2][4096];
  int bx = blockIdx.x;
  int ntile = bx >> 7;
  int mtile = bx & 127;
  int tid = threadIdx.x, lane = tid & 63, w = tid >> 6;

  const unsigned short* ag[2];
  const unsigned short* bgp[2];
  int dofs[2];
#pragma unroll
  for (int a = 0; a < 2; ++a) {
    int rowofs = a * 8 + (lane >> 3);
    int k8 = (lane & 7) ^ (rowofs & 7);
    ag[a] = featb + (size_t)(mtile * 64 + w * 16 + rowofs) * 768 + k8 * 8;
    bgp[a] = w1t + (size_t)(ntile * 64 + w * 16 + rowofs) * 768 + k8 * 8;
    dofs[a] = (w * 128 + a * 64 + lane) * 8;
  }
  int sw0 = (lane >> 4) ^ (lane & 7);
  int sw1 = (4 + (lane >> 4)) ^ (lane & 7);
  int arowc = (w * 16 + (lane & 15)) * 8;
  int colc[4];
#pragma unroll
  for (int ct = 0; ct < 4; ++ct) colc[ct] = (ct * 16 + (lane & 15)) * 8;

  f32x4 acc[4];
#pragma unroll
  for (int ct = 0; ct < 4; ++ct) acc[ct] = (f32x4){0.f, 0.f, 0.f, 0.f};

#pragma unroll
  for (int a = 0; a < 2; ++a) {
    async_copy16(ag[a], &As[0][dofs[a]]); ag[a] += 64;
    async_copy16(bgp[a], &Bs[0][dofs[a]]); bgp[a] += 64;
  }
  __syncthreads();

  for (int it = 0; it < 12; ++it) {
    int cur = it & 1, nxt = cur ^ 1;
    if (it < 11) {
#pragma unroll
      for (int a = 0; a < 2; ++a) {
        async_copy16(ag[a], &As[nxt][dofs[a]]); ag[a] += 64;
        async_copy16(bgp[a], &Bs[nxt][dofs[a]]); bgp[a] += 64;
      }
    }
    const unsigned short* A_ = As[cur];
    const unsigned short* B_ = Bs[cur];
    bf16x8 a0 = *(const bf16x8*)&A_[(arowc + sw0) * 8];
    bf16x8 a1 = *(const bf16x8*)&A_[(arowc + sw1) * 8];
#pragma unroll
    for (int ct = 0; ct < 4; ++ct) {
      bf16x8 b0 = *(const bf16x8*)&B_[(colc[ct] + sw0) * 8];
      acc[ct] = __builtin_amdgcn_mfma_f32_16x16x32_bf16(a0, b0, acc[ct], 0, 0, 0);
    }
#pragma unroll
    for (int ct = 0; ct < 4; ++ct) {
      bf16x8 b1 = *(const bf16x8*)&B_[(colc[ct] + sw1) * 8];
      acc[ct] = __builtin_amdgcn_mfma_f32_16x16x32_bf16(a1, b1, acc[ct], 0, 0, 0);
    }
    __syncthreads();
  }

  float bv[4], w20[4], w21[4];
#pragma unroll
  for (int ct = 0; ct < 4; ++ct) {
    int col = ntile * 64 + ct * 16 + (lane & 15);
    bv[ct] = b1[col]; w20[ct] = w2[col * 2]; w21[ct] = w2[col * 2 + 1];
  }
#pragma unroll
  for (int i = 0; i < 4; ++i) {
    float s0 = 0.f, s1 = 0.f;
#pragma unroll
    for (int ct = 0; ct < 4; ++ct) {
      float r = fmaxf(acc[ct][i] + bv[ct], 0.f);
      s0 += r * w20[ct]; s1 += r * w21[ct];
    }
#pragma unroll
    for (int off = 1; off < 16; off <<= 1) {
      s0 += __shfl_xor(s0, off); s1 += __shfl_xor(s1, off);
    }
    if ((lane & 15) == 0) {
      int row = mtile * 64 + w * 16 + ((lane >> 4) << 2) + i;
      atomicAdd(&logits[row * 2], s0);
      atomicAdd(&logits[row * 2 + 1], s1);
    }
  }
}

// ---------------------------------------------------------------------------
// K3b+K5 fused: select + masked KLDiv loss (unchanged)
// ---------------------------------------------------------------------------
__global__ __launch_bounds__(512) void k_select_loss(
    const float* __restrict__ logits, int* __restrict__ idxv,
    float* __restrict__ mval, int* __restrict__ cmask,
    int* __restrict__ njobs, int* __restrict__ jobs,
    const float* __restrict__ lab, const unsigned char* __restrict__ mask,
    float* __restrict__ out_loss) {
  __shared__ float rs[512], rc[512];
  int tid = threadIdx.x;
  {
    int q = tid;
    int base = q * 16;
    float s[16];
#pragma unroll
    for (int i = 0; i < 16; ++i) s[i] = logits[(size_t)(base + i) * 2 + 1];
    float best = s[0]; int bi = 0;
#pragma unroll
    for (int i = 1; i < 16; ++i) if (s[i] > best) { best = s[i]; bi = i; }
    int msk = 0, cnt = 0;
#pragma unroll
    for (int i = 0; i < 16; ++i) if (s[i] > best - TAU) { msk |= 1 << i; ++cnt; }
    idxv[q] = bi; mval[q] = best;
    if (cnt > 1) {
      cmask[q] = msk;
      int bb = q >> 7;
      for (int i = 0; i < 16; ++i)
        if ((msk >> i) & 1) {
          int j = atomicAdd(&njobs[bb], 1);
          jobs[bb * 2048 + j] = base + i;
        }
    } else cmask[q] = 0;
  }
  float sum = 0.f, cnt = 0.f;
  for (int p = tid; p < 8192; p += 512) {
    float l0 = logits[(size_t)p * 2], l1 = logits[(size_t)p * 2 + 1];
    float a0 = lab[(size_t)p * 2], a1 = lab[(size_t)p * 2 + 1];
    float mx = fmaxf(l0, l1);
    float lse = mx + logf(expf(l0 - mx) + expf(l1 - mx));
    float pw = 0.f;
    if (a0 > 0.f) pw += a0 * logf(fmaxf(a0, 1e-38f));
    if (a1 > 0.f) pw += a1 * logf(fmaxf(a1, 1e-38f));
    pw -= a0 * (l0 - lse) + a1 * (l1 - lse);
    if (mask[p]) { sum += pw; cnt += 1.f; }
  }
  rs[tid] = sum; rc[tid] = cnt;
  __syncthreads();
  for (int s = 256; s > 0; s >>= 1) {
    if (tid < s) { rs[tid] += rs[tid + s]; rc[tid] += rc[tid + s]; }
    __syncthreads();
  }
  if (tid == 0) *out_loss = rs[0] / (rc[0] * 2.0f);
}

// ---------------------------------------------------------------------------
// K3c-A: batched fp32 dot phase (unchanged).
// ---------------------------------------------------------------------------
__global__ __launch_bounds__(1024) void k_refine_dot(
    const int* __restrict__ njobs, const int* __restrict__ jobs,
    const float* __restrict__ head, const float* __restrict__ tail,
    const float* __restrict__ x,
    float* __restrict__ featH, float* __restrict__ featT) {
  __shared__ float red[4][16][256];   // 64KB
  __shared__ int scode[8];
  int tid = threadIdx.x, lane = tid & 63, w = tid >> 6;
  int tg = w >> 2, dg = w & 3;
  int d = dg * 64 + lane;

  for (int gt = blockIdx.x; ; gt += gridDim.x) {
    int rem = gt, b = 0, nj = 0;
    for (; b < 4; ++b) {
      nj = njobs[b];
      int ntb = ((nj + 7) >> 3) * 8;
      if (rem < ntb) break;
      rem -= ntb;
    }
    if (b == 4) break;
    int grp = rem >> 3, tc = rem & 7;
    __syncthreads();
    if (tid < 8) scode[tid] = jobs[b * 2048 + min(grp * 8 + tid, nj - 1)];
    __syncthreads();

    int t0 = tc * 256 + tg * 64;
    float vh[8], vt[8];
#pragma unroll
    for (int j = 0; j < 8; ++j) {
      int p = scode[j] & 2047;
      size_t ro = ((size_t)(b * 2048 + p)) * 2048 + t0 + lane;
      vh[j] = head[ro]; vt[j] = tail[ro];
    }
    float ah[8] = {0.f, 0.f, 0.f, 0.f, 0.f, 0.f, 0.f, 0.f};
    float at[8] = {0.f, 0.f, 0.f, 0.f, 0.f, 0.f, 0.f, 0.f};
    const float* xp = x + (size_t)b * 524288 + (size_t)t0 * 256 + d;
#pragma unroll 8
    for (int t = 0; t < 64; ++t) {
      float xv = xp[(size_t)t * 256];
#pragma unroll
      for (int j = 0; j < 8; ++j) {
        ah[j] += rdlane(vh[j], t) * xv;
        at[j] += rdlane(vt[j], t) * xv;
      }
    }
#pragma unroll
    for (int j = 0; j < 8; ++j) {
      red[tg][j][d] = ah[j];
      red[tg][8 + j][d] = at[j];
    }
    __syncthreads();
    if (tid < 256) {
#pragma unroll
      for (int j = 0; j < 16; ++j) {
        float s = red[0][j][tid] + red[1][j][tid] + red[2][j][tid] + red[3][j][tid];
        int jj = j & 7;
        if (grp * 8 + jj < nj) {
          float* dst = (j < 8) ? featH : featT;
          atomicAdd(&dst[(size_t)scode[jj] * 256 + tid], s);
        }
      }
    }
  }
}

// ---------------------------------------------------------------------------
// K3c-B: batched MLP phase (unchanged).
// ---------------------------------------------------------------------------
__global__ __launch_bounds__(1024) void k_refine_mlp(
    const int* __restrict__ njobs, const int* __restrict__ jobs,
    const float* __restrict__ featH, const float* __restrict__ featT,
    const float* __restrict__ w1, const float* __restrict__ b1,
    const float* __restrict__ w2, const float* __restrict__ b2,
    float* __restrict__ refined) {
  __shared__ float feat8[768][8];     // 24KB
  __shared__ float redm[4][8][256];   // 32KB
  __shared__ float part[8][4];
  __shared__ int scode[8];
  int tid = threadIdx.x;
  int hseg = tid >> 8, d = tid & 255;

  for (int gt = blockIdx.x; ; gt += gridDim.x) {
    int rem = gt, b = 0, nj = 0;
    for (; b < 4; ++b) {
      nj = njobs[b];
      int ntb = (nj + 7) >> 3;
      if (rem < ntb) break;
      rem -= ntb;
    }
    if (b == 4) break;
    int grp = rem;
    __syncthreads();
    if (tid < 8) scode[tid] = jobs[b * 2048 + min(grp * 8 + tid, nj - 1)];
    __syncthreads();
#pragma unroll
    for (int r = 0; r < 2; ++r) {
      int j = hseg * 2 + r;
      float h = featH[(size_t)scode[j] * 256 + d];
      float t = featT[(size_t)scode[j] * 256 + d];
      feat8[d][j] = h; feat8[256 + d][j] = t; feat8[512 + d][j] = h * t;
    }
    __syncthreads();
    float hp[8] = {0.f, 0.f, 0.f, 0.f, 0.f, 0.f, 0.f, 0.f};
    const float* w1c = w1 + (size_t)(hseg * 192) * 256 + d;
#pragma unroll 4
    for (int ii = 0; ii < 192; ++ii) {
      float wv = w1c[(size_t)ii * 256];
      float4 f0 = *(const float4*)&feat8[hseg * 192 + ii][0];
      float4 f1 = *(const float4*)&feat8[hseg * 192 + ii][4];
      hp[0] += f0.x * wv; hp[1] += f0.y * wv; hp[2] += f0.z * wv; hp[3] += f0.w * wv;
      hp[4] += f1.x * wv; hp[5] += f1.y * wv; hp[6] += f1.z * wv; hp[7] += f1.w * wv;
    }
#pragma unroll
    for (int j = 0; j < 8; ++j) redm[hseg][j][d] = hp[j];
    __syncthreads();
    if (tid < 256) {
      float w2v = w2[tid * 2 + 1], b1v = b1[tid];
#pragma unroll
      for (int j = 0; j < 8; ++j) {
        float h = b1v + redm[0][j][tid] + redm[1][j][tid] + redm[2][j][tid] + redm[3][j][tid];
        h = fmaxf(h, 0.f) * w2v;
#pragma unroll
        for (int off = 1; off < 64; off <<= 1) h += __shfl_xor(h, off);
        if ((tid & 63) == 0) part[j][tid >> 6] = h;
      }
    }
    __syncthreads();
    if (tid < 8 && grp * 8 + tid < nj)
      refined[scode[tid]] = part[tid][0] + part[tid][1] + part[tid][2] + part[tid][3] + b2[1];
  }
}

// ---------------------------------------------------------------------------
// K4 (fused repm+merge): out[b][t][d] = x + sum_m cmp[b][m][t] * rep_m[m][d]
// where rep_m is computed in-block from the selection state (one fewer
// kernel launch + no repm round-trip). 512 blocks.
// ---------------------------------------------------------------------------
__global__ __launch_bounds__(256) void k_merge(
    const int* __restrict__ idxv, const float* __restrict__ mval,
    const int* __restrict__ cmask, const float* __restrict__ refined,
    const float* __restrict__ trep,
    const float* __restrict__ cmp, const float* __restrict__ x,
    float* __restrict__ out) {
  __shared__ float cl[128 * 16];
  __shared__ float vs[128];
  __shared__ int bsel[128];
  int bx = blockIdx.x, b = bx >> 7, t0 = (bx & 127) * 16;
  int tid = threadIdx.x;
  if (tid < 128) {   // per-mention select (same math as old k_repm)
    int q = b * 128 + tid;
    int mask = cmask[q]; int bi; float v;
    if (mask) {
      bi = -1; v = -1e30f;
      for (int i = 0; i < 16; ++i)
        if ((mask >> i) & 1) { float s = refined[q * 16 + i]; if (s > v) { v = s; bi = i; } }
    } else { bi = idxv[q]; v = mval[q]; }
    vs[tid] = v; bsel[tid] = bi;
  }
#pragma unroll
  for (int it = 0; it < 2; ++it) {
    int f = it * 256 + tid;
    int row = f >> 2, c4 = (f & 3) * 4;
    *(float4*)&cl[row * 16 + c4] =
        *(const float4*)&cmp[((size_t)(b * 128 + row)) * 2048 + t0 + c4];
  }
  __syncthreads();
  float acc[16];
#pragma unroll
  for (int i = 0; i < 16; ++i) acc[i] = 0.f;
  int d = tid;
  for (int m = 0; m < 128; ++m) {
    size_t trow = ((size_t)(b * 128 + m) * 16 + bsel[m]) * 256;
    float rv = trep[trow + d] * vs[m];
    const float4* c4p = (const float4*)&cl[m * 16];
#pragma unroll
    for (int jj = 0; jj < 4; ++jj) {
      float4 c = c4p[jj];
      acc[jj * 4] += c.x * rv; acc[jj * 4 + 1] += c.y * rv;
      acc[jj * 4 + 2] += c.z * rv; acc[jj * 4 + 3] += c.w * rv;
    }
  }
  const float* xb = x + ((size_t)(b * 2048 + t0)) * 256 + d;
  float* ob = out + ((size_t)(b * 2048 + t0)) * 256 + d;
#pragma unroll
  for (int tt = 0; tt < 16; ++tt) ob[(size_t)tt * 256] = xb[(size_t)tt * 256] + acc[tt];
}

// ---------------------------------------------------------------------------
extern "C" void kernel_launch(void* const* d_in, const int* in_sizes, int n_in,
                              void* d_out, int out_size, void* d_ws, size_t ws_size,
                              hipStream_t stream) {
  (void)in_sizes; (void)n_in; (void)out_size; (void)ws_size;
  const float* head = (const float*)d_in[0];
  const float* tail = (const float*)d_in[1];
  // d_in[2] = lens (uniform L=16) -- unused
  const float* x = (const float*)d_in[3];
  const float* cmp = (const float*)d_in[4];
  const float* lab = (const float*)d_in[5];
  const unsigned char* lmask = (const unsigned char*)d_in[6];
  const float* w1 = (const float*)d_in[7];
  const float* b1 = (const float*)d_in[8];
  const float* w2 = (const float*)d_in[9];
  const float* b2 = (const float*)d_in[10];
  float* out = (float*)d_out;

  char* ws = (char*)d_ws;
  size_t off = 0;
  auto alloc = [&](size_t bytes) -> void* {
    void* p = ws + off; off += (bytes + 255) & ~(size_t)255; return p;
  };
  unsigned short* xt = (unsigned short*)alloc(4ull * 256 * 2048 * 2);
  unsigned short* w1t = (unsigned short*)alloc(256ull * 768 * 2);
  float* hrep = (float*)alloc(8192ull * 256 * 4);
  float* trep = (float*)alloc(8192ull * 256 * 4);
  unsigned short* featb = (unsigned short*)alloc(8192ull * 768 * 2);
  float* logits = (float*)alloc(8192ull * 2 * 4);
  float* refined = (float*)alloc(8192ull * 4);
  int* idxv = (int*)alloc(512 * 4);
  float* mvalv = (float*)alloc(512 * 4);
  int* cmaskv = (int*)alloc(512 * 4);
  int* njobs = (int*)alloc(256);
  int* jobs = (int*)alloc(4 * 2048 * 4);
  float* featH = (float*)alloc(8192ull * 256 * 4);   // contiguous with featT
  float* featT = (float*)alloc(8192ull * 256 * 4);

  k_prep<<<304, 256, 0, stream>>>(x, w1, b2, xt, w1t, logits, njobs, featH);
  k_gemm_rep<<<512, 512, 0, stream>>>(head, tail, xt, hrep, trep);
  k_feat<<<2048, 256, 0, stream>>>(hrep, trep, featb);
  k_gemm_mlp<<<512, 256, 0, stream>>>(featb, w1t, b1, w2, logits);
  k_select_loss<<<1, 512, 0, stream>>>(logits, idxv, mvalv, cmaskv, njobs, jobs,
                                       lab, lmask, out + 4ull * 2048 * 256);
  k_refine_dot<<<512, 1024, 0, stream>>>(njobs, jobs, head, tail, x, featH, featT);
  k_refine_mlp<<<128, 1024, 0, stream>>>(njobs, jobs, featH, featT, w1, b1, w2, b2, refined);
  k_merge<<<512, 256, 0, stream>>>(idxv, mvalv, cmaskv, refined, trep, cmp, x, out);
}